// Round 1
// baseline (1038.703 us; speedup 1.0000x reference)
//
#include <hip/hip_runtime.h>
#include <math.h>

#define B 2
#define S 1024
#define DIM 512
#define H 8
#define HD 64
#define EPS 1e-5f

// ---------------- GEMM: C[M,N] = A[M,K] @ W[K,N] + bias ----------------
// MODE 0: out[m*N+n] = acc + bias[n]
// MODE 1: projection scatter: b=m>>10, s=m&1023, h=n>>6, d=n&63
//         out[((b*H+h)*S+s)*HD+d] = (acc + bias[n]) * scale
template<int MODE>
__global__ void gemm512(const float* __restrict__ A, const float* __restrict__ W,
                        const float* __restrict__ bias, float* __restrict__ out,
                        int M, int N, int K, float scale)
{
    const int BM = 64, BN = 64, BK = 32;
    __shared__ float As[BK][BM + 1];
    __shared__ float Ws[BK][BN + 1];
    int tid = threadIdx.x;            // 256 threads
    int tx = tid & 15, ty = tid >> 4; // 16x16
    int m0 = blockIdx.x * BM, n0 = blockIdx.y * BN;
    float acc[4][4] = {};
    for (int k0 = 0; k0 < K; k0 += BK) {
        // A tile 64x32 (stored transposed)
        int kkA = tid & 31;
        int mmA = tid >> 5;
        #pragma unroll
        for (int i = 0; i < 8; ++i)
            As[kkA][mmA + i * 8] = A[(m0 + mmA + i * 8) * K + k0 + kkA];
        // W tile 32x64
        int nnW = tid & 63;
        int kkW = tid >> 6;
        #pragma unroll
        for (int i = 0; i < 8; ++i)
            Ws[kkW + i * 4][nnW] = W[(k0 + kkW + i * 4) * N + n0 + nnW];
        __syncthreads();
        #pragma unroll
        for (int kk = 0; kk < BK; ++kk) {
            float a[4], w[4];
            #pragma unroll
            for (int i = 0; i < 4; ++i) a[i] = As[kk][ty * 4 + i];
            #pragma unroll
            for (int j = 0; j < 4; ++j) w[j] = Ws[kk][tx * 4 + j];
            #pragma unroll
            for (int i = 0; i < 4; ++i)
                #pragma unroll
                for (int j = 0; j < 4; ++j)
                    acc[i][j] += a[i] * w[j];
        }
        __syncthreads();
    }
    #pragma unroll
    for (int i = 0; i < 4; ++i)
        #pragma unroll
        for (int j = 0; j < 4; ++j) {
            int m = m0 + ty * 4 + i, n = n0 + tx * 4 + j;
            float val = acc[i][j] + bias[n];
            if (MODE == 0) {
                out[m * N + n] = val;
            } else {
                int b = m >> 10, s = m & 1023, hh = n >> 6, d = n & 63;
                out[(((b * H) + hh) * S + s) * HD + d] = val * scale;
            }
        }
}

// ---------------- causal Toeplitz conv along s, per (b,h) ----------------
// dst[t,d] = sum_{tau<=t} f[tau,h] * src[t-tau,d]
__global__ void conv_kernel(const float* __restrict__ src, const float* __restrict__ filt,
                            float* __restrict__ dst)
{
    int tb = blockIdx.x;       // 16 t-blocks of 64
    int bh = blockIdx.y;       // 16 (b,h)
    int h = bh & (H - 1);
    int tx = threadIdx.x;      // 64 (= d)
    int ty = threadIdx.y;      // 4
    int tid = ty * 64 + tx;
    __shared__ float kt[64][65];
    __shared__ float fl[128];
    float acc[16] = {};
    const float* srcb = src + bh * S * HD;
    for (int sb = 0; sb <= tb; ++sb) {
        #pragma unroll
        for (int i = 0; i < 16; ++i) {
            int srow = ty + 4 * i;
            kt[srow][tx] = srcb[(sb * 64 + srow) * HD + tx];
        }
        if (tid < 128) {
            int idx = (tb - sb) * 64 + tid - 63;
            fl[tid] = (idx >= 0 && idx < S) ? filt[idx * H + h] : 0.f;
        }
        __syncthreads();
        for (int s = 0; s < 64; ++s) {
            float kv = kt[s][tx];
            #pragma unroll
            for (int i = 0; i < 16; ++i) {
                int t = ty + 4 * i;
                acc[i] += fl[63 + t - s] * kv;
            }
        }
        __syncthreads();
    }
    float* dstb = dst + bh * S * HD;
    #pragma unroll
    for (int i = 0; i < 16; ++i) {
        int t = tb * 64 + ty + 4 * i;
        dstb[t * HD + tx] = acc[i];
    }
}

// ---------------- gates + prefix sum, per (b,h) ----------------
__global__ void gates_kernel(const float* __restrict__ kc, const float* __restrict__ vc,
                             const float* __restrict__ gw, const float* __restrict__ gb,
                             float* __restrict__ gates, float* __restrict__ cumg)
{
    int bh = blockIdx.x;
    int tx = threadIdx.x;  // 64
    int ty = threadIdx.y;  // 4
    int tid = ty * 64 + tx;
    __shared__ float G[64][65];
    __shared__ float kl[4][64];
    __shared__ float ga[1024];
    __shared__ float gbuf[1024];
    for (int idx = tid; idx < 4096; idx += 256)
        G[idx >> 6][idx & 63] = gw[idx];
    __syncthreads();
    const float* kb = kc + bh * S * HD;
    const float* vb = vc + bh * S * HD;
    float gbias = gb[0];
    for (int s0 = 0; s0 < S; s0 += 4) {
        int s = s0 + ty;
        float ke = kb[s * HD + tx];
        float vd = vb[s * HD + tx];
        kl[ty][tx] = ke;
        __syncthreads();
        float t = 0.f;
        #pragma unroll
        for (int e = 0; e < 64; ++e) t += G[tx][e] * kl[ty][e];
        float p = vd * t;
        #pragma unroll
        for (int off = 32; off >= 1; off >>= 1) p += __shfl_xor(p, off);
        if (tx == 0) {
            float g = fmaxf(p + gbias, 0.f);
            ga[s] = g * g + EPS;
        }
        __syncthreads();
    }
    __syncthreads();
    for (int idx = tid; idx < 1024; idx += 256) gates[bh * S + idx] = ga[idx];
    // inclusive scan (Hillis-Steele, ping-pong)
    float* srcp = ga;
    float* dstp = gbuf;
    for (int off = 1; off < 1024; off <<= 1) {
        __syncthreads();
        for (int idx = tid; idx < 1024; idx += 256)
            dstp[idx] = srcp[idx] + (idx >= off ? srcp[idx - off] : 0.f);
        float* tmp = srcp; srcp = dstp; dstp = tmp;
    }
    __syncthreads();
    for (int idx = tid; idx < 1024; idx += 256) cumg[bh * S + idx] = srcp[idx];
}

// ---------------- causal gated linear attention, per (b,h, t-block) ----------------
__global__ void attn_kernel(const float* __restrict__ q, const float* __restrict__ kc,
                            const float* __restrict__ vc, const float* __restrict__ gates,
                            const float* __restrict__ cumg, float* __restrict__ y)
{
    int tb = blockIdx.x;   // 16
    int bh = blockIdx.y;   // 16
    int b = bh >> 3, h = bh & 7;
    int tx = threadIdx.x;  // 64
    int ty = threadIdx.y;  // 4
    __shared__ float Qb[64][65];
    __shared__ float VK[64][65];
    __shared__ float SC[64][65];
    __shared__ float gl[64];
    const float* qb = q + bh * S * HD;
    const float* kb = kc + bh * S * HD;
    const float* vb = vc + bh * S * HD;
    #pragma unroll
    for (int i = 0; i < 16; ++i) {
        int t = ty + 4 * i;
        Qb[t][tx] = qb[(tb * 64 + t) * HD + tx];
    }
    float acc[16] = {};
    for (int sb = 0; sb <= tb; ++sb) {
        __syncthreads();   // protect VK/SC from previous iteration
        #pragma unroll
        for (int i = 0; i < 16; ++i) {
            int srow = ty + 4 * i;
            VK[srow][tx] = vb[(sb * 64 + srow) * HD + tx];
        }
        if (ty == 0) gl[tx] = gates[bh * S + sb * 64 + tx];
        __syncthreads();
        // stage1: scores (with gate + causal mask folded in)
        #pragma unroll
        for (int i = 0; i < 16; ++i) {
            int t = ty + 4 * i;
            float dot = 0.f;
            for (int d = 0; d < 64; ++d) dot += Qb[t][d] * VK[tx][d];
            int tg = tb * 64 + t, sg = sb * 64 + tx;
            SC[t][tx] = (sg <= tg) ? dot * gl[tx] : 0.f;
        }
        __syncthreads();
        #pragma unroll
        for (int i = 0; i < 16; ++i) {
            int srow = ty + 4 * i;
            VK[srow][tx] = kb[(sb * 64 + srow) * HD + tx];
        }
        __syncthreads();
        // stage2: out += SC @ K
        for (int s = 0; s < 64; ++s) {
            float kv = VK[s][tx];
            #pragma unroll
            for (int i = 0; i < 16; ++i)
                acc[i] += SC[ty + 4 * i][s] * kv;
        }
    }
    // epilogue: divide by cumg, unit-normalize rows (over e), scatter to y[b,s,dim]
    #pragma unroll
    for (int i = 0; i < 16; ++i) {
        int t = ty + 4 * i;
        int tg = tb * 64 + t;
        float cg = cumg[bh * S + tg];
        float val = acc[i] / (cg + EPS);
        float sq = val * val;
        #pragma unroll
        for (int off = 32; off >= 1; off >>= 1) sq += __shfl_xor(sq, off);
        float nrm = sqrtf(sq);
        val = val / fmaxf(nrm, EPS);
        y[(b * S + tg) * DIM + h * HD + tx] = val;
    }
}

extern "C" void kernel_launch(void* const* d_in, const int* in_sizes, int n_in,
                              void* d_out, int out_size, void* d_ws, size_t ws_size,
                              hipStream_t stream) {
    const float* x    = (const float*)d_in[0];
    const float* sbas = (const float*)d_in[1];
    const float* wq_w = (const float*)d_in[2];
    const float* wq_b = (const float*)d_in[3];
    const float* wk_w = (const float*)d_in[4];
    const float* wk_b = (const float*)d_in[5];
    const float* wv_w = (const float*)d_in[6];
    const float* wv_b = (const float*)d_in[7];
    const float* wo_w = (const float*)d_in[8];
    const float* wo_b = (const float*)d_in[9];
    const float* gw   = (const float*)d_in[10];
    const float* gb   = (const float*)d_in[11];
    float* out = (float*)d_out;
    float* ws  = (float*)d_ws;

    const size_t T = (size_t)B * H * S * HD;  // 1,048,576
    float* q     = ws;
    float* k     = q + T;
    float* v     = k + T;
    float* kc    = v + T;
    float* vc    = kc + T;
    float* gates = vc + T;
    float* cumg  = gates + B * H * S;
    float* y     = cumg + B * H * S;

    dim3 gridG(32, 8), blockG(256);
    dim3 gridC(16, 16), blockC(64, 4);

    // projections
    gemm512<1><<<gridG, blockG, 0, stream>>>(x, wq_w, wq_b, q, 2048, 512, 512, 1.0f);
    gemm512<1><<<gridG, blockG, 0, stream>>>(x, wk_w, wk_b, k, 2048, 512, 512, 0.125f);
    gemm512<1><<<gridG, blockG, 0, stream>>>(x, wv_w, wv_b, v, 2048, 512, 512, 1.0f);
    // causal spectral convolutions
    conv_kernel<<<gridC, blockC, 0, stream>>>(k, sbas, kc);
    conv_kernel<<<gridC, blockC, 0, stream>>>(v, sbas, vc);
    // gates + prefix sums
    gates_kernel<<<dim3(16), dim3(64, 4), 0, stream>>>(kc, vc, gw, gb, gates, cumg);
    // causal gated linear attention + normalization
    attn_kernel<<<gridC, blockC, 0, stream>>>(q, kc, vc, gates, cumg, y);
    // output projection
    gemm512<0><<<gridG, blockG, 0, stream>>>(y, wo_w, wo_b, out, 2048, 512, 512, 1.0f);
}

// Round 3
// 231.811 us; speedup vs baseline: 4.4808x; 4.4808x over previous
//
#include <hip/hip_runtime.h>
#include <math.h>

#define B 2
#define S 1024
#define DIM 512
#define H 8
#define HD 64
#define EPS 1e-5f

typedef __attribute__((ext_vector_type(8))) short bf16x8;
typedef __attribute__((ext_vector_type(4))) float f32x4;
typedef unsigned short u16;

__device__ inline u16 f2bf(float f) {
    unsigned int u = __float_as_uint(f);
    return (u16)((u + 0x7FFF + ((u >> 16) & 1)) >> 16);
}
__device__ inline float bf2f(u16 v) {
    return __uint_as_float(((unsigned int)v) << 16);
}
__device__ inline void split2(float x, u16* hi, u16* lo) {
    u16 h = f2bf(x);
    *hi = h;
    *lo = f2bf(x - bf2f(h));
}
#define MFMA16(a, b, c) __builtin_amdgcn_mfma_f32_16x16x32_bf16((a), (b), (c), 0, 0, 0)

// ---------------- x fp32 -> hi/lo bf16 planes ----------------
__global__ void xconv_k(const float* __restrict__ x, u16* __restrict__ xh, u16* __restrict__ xl) {
    int i = blockIdx.x * 256 + threadIdx.x;   // one float4 per thread
    float4 v = ((const float4*)x)[i];
    ushort4 h, l;
    split2(v.x, &h.x, &l.x); split2(v.y, &h.y, &l.y);
    split2(v.z, &h.z, &l.z); split2(v.w, &h.w, &l.w);
    ((ushort4*)xh)[i] = h; ((ushort4*)xl)[i] = l;
}

// ---------------- weights: [K][N] f32 -> [N][K] hi/lo bf16 ----------------
__global__ void wconv_k(const float* __restrict__ wq, const float* __restrict__ wk,
                        const float* __restrict__ wv, const float* __restrict__ wo,
                        u16* __restrict__ wqkvh, u16* __restrict__ wqkvl,
                        u16* __restrict__ woh, u16* __restrict__ wol) {
    int z = blockIdx.z;
    const float* src = (z == 0) ? wq : (z == 1) ? wk : (z == 2) ? wv : wo;
    u16* dh = (z < 3) ? (wqkvh + (size_t)z * 512 * 512) : woh;
    u16* dl = (z < 3) ? (wqkvl + (size_t)z * 512 * 512) : wol;
    int k0 = blockIdx.x * 64, n0 = blockIdx.y * 64;
    int tid = threadIdx.x;
    __shared__ float T[64][65];
    #pragma unroll
    for (int p = 0; p < 16; ++p) {
        int i = tid + 256 * p; int r = i >> 6, c = i & 63;
        T[r][c] = src[(k0 + r) * 512 + n0 + c];
    }
    __syncthreads();
    #pragma unroll
    for (int p = 0; p < 16; ++p) {
        int i = tid + 256 * p; int r = i >> 6, c = i & 63;
        size_t di = (size_t)(n0 + r) * 512 + k0 + c;
        split2(T[c][r], &dh[di], &dl[di]);
    }
}

// ---------------- QKV GEMM (split bf16): C = x @ Wt, scatter q/k/v ----------------
__global__ void qkv_gemm(const u16* __restrict__ Ah, const u16* __restrict__ Al,
                         const u16* __restrict__ Bh, const u16* __restrict__ Bl,
                         const float* __restrict__ bq, const float* __restrict__ bk,
                         const float* __restrict__ bv,
                         u16* __restrict__ qh, u16* __restrict__ ql,
                         u16* __restrict__ kth, u16* __restrict__ ktl,
                         u16* __restrict__ vth, u16* __restrict__ vtl) {
    const int K = 512;
    __shared__ __align__(16) u16 Ash[64][72], Asl[64][72], Bsh[64][72], Bsl[64][72];
    int tid = threadIdx.x, w = tid >> 6, l = tid & 63;
    int m0 = blockIdx.x * 64, n0 = blockIdx.y * 64;
    f32x4 acc[4] = {};
    for (int k0 = 0; k0 < K; k0 += 64) {
        #pragma unroll
        for (int p = 0; p < 2; ++p) {
            int i = tid + 256 * p; int r = i >> 3, c8 = (i & 7) * 8;
            *(bf16x8*)&Ash[r][c8] = *(const bf16x8*)&Ah[(size_t)(m0 + r) * K + k0 + c8];
            *(bf16x8*)&Asl[r][c8] = *(const bf16x8*)&Al[(size_t)(m0 + r) * K + k0 + c8];
            *(bf16x8*)&Bsh[r][c8] = *(const bf16x8*)&Bh[(size_t)(n0 + r) * K + k0 + c8];
            *(bf16x8*)&Bsl[r][c8] = *(const bf16x8*)&Bl[(size_t)(n0 + r) * K + k0 + c8];
        }
        __syncthreads();
        #pragma unroll
        for (int kc = 0; kc < 2; ++kc) {
            int ar = 16 * w + (l & 15), ac = kc * 32 + (l >> 4) * 8;
            bf16x8 ah = *(const bf16x8*)&Ash[ar][ac];
            bf16x8 al = *(const bf16x8*)&Asl[ar][ac];
            #pragma unroll
            for (int cf = 0; cf < 4; ++cf) {
                int br = cf * 16 + (l & 15);
                bf16x8 bh_ = *(const bf16x8*)&Bsh[br][ac];
                bf16x8 bl_ = *(const bf16x8*)&Bsl[br][ac];
                acc[cf] = MFMA16(ah, bh_, acc[cf]);
                acc[cf] = MFMA16(ah, bl_, acc[cf]);
                acc[cf] = MFMA16(al, bh_, acc[cf]);
            }
        }
        __syncthreads();
    }
    #pragma unroll
    for (int cf = 0; cf < 4; ++cf) {
        #pragma unroll
        for (int r = 0; r < 4; ++r) {
            int m = m0 + 16 * w + 4 * (l >> 4) + r;
            int n = n0 + 16 * cf + (l & 15);
            int bb = m >> 10, s = m & 1023;
            int which = n >> 9, nn = n & 511;
            int hh = nn >> 6, d = nn & 63;
            int bh = bb * 8 + hh;
            float val = acc[cf][r];
            if (which == 0) {
                val += bq[nn];
                size_t di = ((size_t)bh * 1024 + s) * 64 + d;
                split2(val, &qh[di], &ql[di]);
            } else if (which == 1) {
                val = (val + bk[nn]) * 0.125f;
                size_t di = ((size_t)bh * 64 + d) * 1024 + s;
                split2(val, &kth[di], &ktl[di]);
            } else {
                val += bv[nn];
                size_t di = ((size_t)bh * 64 + d) * 1024 + s;
                split2(val, &vth[di], &vtl[di]);
            }
        }
    }
}

// ---------------- causal spectral conv (split bf16 Toeplitz MFMA, K+V fused) ----------------
__global__ void conv_mfma(const u16* __restrict__ kth, const u16* __restrict__ ktl,
                          const u16* __restrict__ vth, const u16* __restrict__ vtl,
                          const float* __restrict__ filt,
                          u16* __restrict__ kcrh, u16* __restrict__ kcrl,
                          u16* __restrict__ kcth, u16* __restrict__ kctl,
                          u16* __restrict__ vcrh, u16* __restrict__ vcrl,
                          u16* __restrict__ vcth, u16* __restrict__ vctl) {
    int tb = blockIdx.x, bh = blockIdx.y, h = bh & 7;
    int tid = threadIdx.x, w = tid >> 6, l = tid & 63;
    __shared__ __align__(16) u16 Ksh[64][72], Ksl[64][72], Vsh[64][72], Vsl[64][72];
    __shared__ u16 fh[128], fl[128];
    f32x4 aK[4] = {}, aV[4] = {};
    const size_t base = (size_t)bh * 64 * 1024;
    for (int sb = 0; sb <= tb; ++sb) {
        if (tid < 128) {
            int idx = (tb - sb) * 64 + 64 - tid;
            float fv = (idx >= 0 && idx < S) ? filt[idx * H + h] : 0.f;
            split2(fv, &fh[tid], &fl[tid]);
        }
        #pragma unroll
        for (int p = 0; p < 2; ++p) {
            int i = tid + 256 * p; int r = i >> 3, c8 = (i & 7) * 8;
            *(bf16x8*)&Ksh[r][c8] = *(const bf16x8*)&kth[base + r * 1024 + sb * 64 + c8];
            *(bf16x8*)&Ksl[r][c8] = *(const bf16x8*)&ktl[base + r * 1024 + sb * 64 + c8];
            *(bf16x8*)&Vsh[r][c8] = *(const bf16x8*)&vth[base + r * 1024 + sb * 64 + c8];
            *(bf16x8*)&Vsl[r][c8] = *(const bf16x8*)&vtl[base + r * 1024 + sb * 64 + c8];
        }
        __syncthreads();
        #pragma unroll
        for (int kc = 0; kc < 2; ++kc) {
            int tA = 16 * w + (l & 15);
            int s0 = kc * 32 + (l >> 4) * 8;
            int bidx = 64 + s0 - tA;
            bf16x8 ah, al;
            #pragma unroll
            for (int q = 0; q < 8; ++q) { ah[q] = (short)fh[bidx + q]; al[q] = (short)fl[bidx + q]; }
            #pragma unroll
            for (int cf = 0; cf < 4; ++cf) {
                int br = cf * 16 + (l & 15), bc = kc * 32 + (l >> 4) * 8;
                bf16x8 kh8 = *(const bf16x8*)&Ksh[br][bc];
                bf16x8 kl8 = *(const bf16x8*)&Ksl[br][bc];
                bf16x8 vh8 = *(const bf16x8*)&Vsh[br][bc];
                bf16x8 vl8 = *(const bf16x8*)&Vsl[br][bc];
                aK[cf] = MFMA16(ah, kh8, aK[cf]);
                aK[cf] = MFMA16(ah, kl8, aK[cf]);
                aK[cf] = MFMA16(al, kh8, aK[cf]);
                aV[cf] = MFMA16(ah, vh8, aV[cf]);
                aV[cf] = MFMA16(ah, vl8, aV[cf]);
                aV[cf] = MFMA16(al, vh8, aV[cf]);
            }
        }
        __syncthreads();
    }
    #pragma unroll
    for (int cf = 0; cf < 4; ++cf) {
        #pragma unroll
        for (int r = 0; r < 4; ++r) {
            int tl_ = 16 * w + 4 * (l >> 4) + r;
            int t = tb * 64 + tl_;
            int d = cf * 16 + (l & 15);
            float kv = aK[cf][r], vv = aV[cf][r];
            size_t ri = ((size_t)bh * 1024 + t) * 64 + d;    // row-major
            size_t ti = ((size_t)bh * 64 + d) * 1024 + t;    // transposed
            split2(kv, &kcrh[ri], &kcrl[ri]);
            split2(kv, &kcth[ti], &kctl[ti]);
            split2(vv, &vcrh[ri], &vcrl[ri]);
            split2(vv, &vcth[ti], &vctl[ti]);
        }
    }
}

// ---------------- gates: g = relu(vhat.(G khat) + gb)^2 + EPS ----------------
__global__ void gates_k(const u16* __restrict__ kcrh, const u16* __restrict__ kcrl,
                        const u16* __restrict__ vcrh, const u16* __restrict__ vcrl,
                        const float* __restrict__ gw, const float* __restrict__ gb,
                        float* __restrict__ g) {
    int sc_ = blockIdx.x, bh = blockIdx.y;
    int tid = threadIdx.x, tx = tid & 63, ty = tid >> 6;
    __shared__ float G[64][65];
    __shared__ float kl[4][64];
    for (int i = tid; i < 4096; i += 256) G[i >> 6][i & 63] = gw[i];
    __syncthreads();
    float gbias = gb[0];
    for (int it = 0; it < 16; ++it) {
        int s = sc_ * 64 + it * 4 + ty;
        size_t idx = ((size_t)bh * 1024 + s) * 64 + tx;
        float ke = bf2f(kcrh[idx]) + bf2f(kcrl[idx]);
        float vd = bf2f(vcrh[idx]) + bf2f(vcrl[idx]);
        kl[ty][tx] = ke;
        __syncthreads();
        float t = 0.f;
        #pragma unroll
        for (int e = 0; e < 64; ++e) t += G[tx][e] * kl[ty][e];
        float p = vd * t;
        #pragma unroll
        for (int off = 32; off >= 1; off >>= 1) p += __shfl_xor(p, off);
        if (tx == 0) { float gg = fmaxf(p + gbias, 0.f); g[(size_t)bh * 1024 + s] = gg * gg + EPS; }
        __syncthreads();
    }
}

// ---------------- inclusive scan of g -> cumg per bh ----------------
__global__ void scan_k(const float* __restrict__ g, float* __restrict__ cumg) {
    int bh = blockIdx.x; int tid = threadIdx.x;
    __shared__ float a0[1024], a1[1024];
    for (int i = tid; i < 1024; i += 256) a0[i] = g[(size_t)bh * 1024 + i];
    float *sp = a0, *dp = a1;
    for (int off = 1; off < 1024; off <<= 1) {
        __syncthreads();
        for (int i = tid; i < 1024; i += 256) dp[i] = sp[i] + (i >= off ? sp[i - off] : 0.f);
        float* tmp = sp; sp = dp; dp = tmp;
    }
    __syncthreads();
    for (int i = tid; i < 1024; i += 256) cumg[(size_t)bh * 1024 + i] = sp[i];
}

// ---------------- per-block states M[e][d] = sum_s g_s khat[s][e] vhat[s][d] ----------------
__global__ void states_mfma(const u16* __restrict__ kcth, const u16* __restrict__ kctl,
                            const u16* __restrict__ vcth, const u16* __restrict__ vctl,
                            const float* __restrict__ g, float* __restrict__ Mst) {
    int j = blockIdx.x, bh = blockIdx.y;
    int tid = threadIdx.x, w = tid >> 6, l = tid & 63;
    __shared__ __align__(16) u16 Ash[64][72], Asl[64][72], Bsh[64][72], Bsl[64][72];
    __shared__ float gs[64];
    if (tid < 64) gs[tid] = g[(size_t)bh * 1024 + j * 64 + tid];
    __syncthreads();
    #pragma unroll
    for (int p = 0; p < 2; ++p) {
        int i = tid + 256 * p; int r = i >> 3, c8 = (i & 7) * 8;
        bf16x8 kh8 = *(const bf16x8*)&kcth[((size_t)bh * 64 + r) * 1024 + j * 64 + c8];
        bf16x8 kl8 = *(const bf16x8*)&kctl[((size_t)bh * 64 + r) * 1024 + j * 64 + c8];
        #pragma unroll
        for (int q = 0; q < 8; ++q) {
            float f = (bf2f((u16)kh8[q]) + bf2f((u16)kl8[q])) * gs[c8 + q];
            split2(f, &Ash[r][c8 + q], &Asl[r][c8 + q]);
        }
        *(bf16x8*)&Bsh[r][c8] = *(const bf16x8*)&vcth[((size_t)bh * 64 + r) * 1024 + j * 64 + c8];
        *(bf16x8*)&Bsl[r][c8] = *(const bf16x8*)&vctl[((size_t)bh * 64 + r) * 1024 + j * 64 + c8];
    }
    __syncthreads();
    f32x4 acc[4] = {};
    #pragma unroll
    for (int kc = 0; kc < 2; ++kc) {
        int ar = 16 * w + (l & 15), ac = kc * 32 + (l >> 4) * 8;
        bf16x8 ah = *(const bf16x8*)&Ash[ar][ac];
        bf16x8 al = *(const bf16x8*)&Asl[ar][ac];
        #pragma unroll
        for (int cf = 0; cf < 4; ++cf) {
            int br = cf * 16 + (l & 15);
            bf16x8 bh_ = *(const bf16x8*)&Bsh[br][ac];
            bf16x8 bl_ = *(const bf16x8*)&Bsl[br][ac];
            acc[cf] = MFMA16(ah, bh_, acc[cf]);
            acc[cf] = MFMA16(ah, bl_, acc[cf]);
            acc[cf] = MFMA16(al, bh_, acc[cf]);
        }
    }
    #pragma unroll
    for (int cf = 0; cf < 4; ++cf) {
        #pragma unroll
        for (int r = 0; r < 4; ++r) {
            int e = 16 * w + 4 * (l >> 4) + r;
            int d = cf * 16 + (l & 15);
            Mst[(((size_t)bh * 16 + j) * 64 + e) * 64 + d] = acc[cf][r];
        }
    }
}

// ---------------- exclusive prefix over j -> hi/lo bf16 ----------------
__global__ void state_prefix(const float* __restrict__ Mst,
                             u16* __restrict__ ph, u16* __restrict__ pl) {
    int bh = blockIdx.x; int tid = threadIdx.x;
    for (int p0 = 0; p0 < 16; ++p0) {
        int pos = p0 * 256 + tid;
        float run = 0.f;
        #pragma unroll
        for (int j = 0; j < 16; ++j) {
            size_t idx = ((size_t)bh * 16 + j) * 4096 + pos;
            split2(run, &ph[idx], &pl[idx]);
            run += Mst[idx];
        }
    }
}

// ---------------- attention: out = Q@Pex + intra, /(cumg+eps), unit-norm ----------------
__global__ void attn_mfma(const u16* __restrict__ qh, const u16* __restrict__ ql,
                          const u16* __restrict__ pexh, const u16* __restrict__ pexl,
                          const u16* __restrict__ vcrh, const u16* __restrict__ vcrl,
                          const u16* __restrict__ kcth, const u16* __restrict__ kctl,
                          const float* __restrict__ g, const float* __restrict__ cumg,
                          u16* __restrict__ yh, u16* __restrict__ yl) {
    int tb = blockIdx.x, bh = blockIdx.y;
    int b = bh >> 3, h = bh & 7;
    int tid = threadIdx.x, w = tid >> 6, l = tid & 63;
    // phase A: buf0=Qh buf1=Ql buf2=Ph buf3=Pl buf4=Vrh buf5=Vrl
    // phase B: buf2=Sch buf3=Scl buf4=Kth buf5=Ktl
    __shared__ __align__(16) u16 buf[6][64][72];
    __shared__ float gl_s[64], cg_s[64];
    #pragma unroll
    for (int p = 0; p < 2; ++p) {
        int i = tid + 256 * p; int r = i >> 3, c8 = (i & 7) * 8;
        size_t rowi = ((size_t)bh * 1024 + tb * 64 + r) * 64 + c8;
        size_t pexi = (((size_t)bh * 16 + tb) * 64 + r) * 64 + c8;
        *(bf16x8*)&buf[0][r][c8] = *(const bf16x8*)&qh[rowi];
        *(bf16x8*)&buf[1][r][c8] = *(const bf16x8*)&ql[rowi];
        *(bf16x8*)&buf[2][r][c8] = *(const bf16x8*)&pexh[pexi];
        *(bf16x8*)&buf[3][r][c8] = *(const bf16x8*)&pexl[pexi];
        *(bf16x8*)&buf[4][r][c8] = *(const bf16x8*)&vcrh[rowi];
        *(bf16x8*)&buf[5][r][c8] = *(const bf16x8*)&vcrl[rowi];
    }
    if (tid < 64) {
        gl_s[tid] = g[(size_t)bh * 1024 + tb * 64 + tid];
        cg_s[tid] = cumg[(size_t)bh * 1024 + tb * 64 + tid];
    }
    __syncthreads();
    f32x4 o[4] = {}, sc[4] = {};
    #pragma unroll
    for (int kc = 0; kc < 2; ++kc) {
        int ar = 16 * w + (l & 15), ac = kc * 32 + (l >> 4) * 8;
        bf16x8 ah = *(const bf16x8*)&buf[0][ar][ac];
        bf16x8 al = *(const bf16x8*)&buf[1][ar][ac];
        #pragma unroll
        for (int cf = 0; cf < 4; ++cf) {
            int br = cf * 16 + (l & 15);
            bf16x8 bph = *(const bf16x8*)&buf[2][br][ac];
            bf16x8 bpl = *(const bf16x8*)&buf[3][br][ac];
            bf16x8 bvh = *(const bf16x8*)&buf[4][br][ac];
            bf16x8 bvl = *(const bf16x8*)&buf[5][br][ac];
            o[cf] = MFMA16(ah, bph, o[cf]);
            o[cf] = MFMA16(ah, bpl, o[cf]);
            o[cf] = MFMA16(al, bph, o[cf]);
            sc[cf] = MFMA16(ah, bvh, sc[cf]);
            sc[cf] = MFMA16(ah, bvl, sc[cf]);
            sc[cf] = MFMA16(al, bvh, sc[cf]);
        }
    }
    __syncthreads();
    // write gated+masked scores (split) into buf2/3; load K^T into buf4/5
    #pragma unroll
    for (int cf = 0; cf < 4; ++cf) {
        int s = cf * 16 + (l & 15);
        float gsv = gl_s[s];
        #pragma unroll
        for (int r = 0; r < 4; ++r) {
            int t = 16 * w + 4 * (l >> 4) + r;
            float v = (s <= t) ? sc[cf][r] * gsv : 0.f;
            split2(v, &buf[2][t][s], &buf[3][t][s]);
        }
    }
    #pragma unroll
    for (int p = 0; p < 2; ++p) {
        int i = tid + 256 * p; int r = i >> 3, c8 = (i & 7) * 8;
        size_t ti = ((size_t)bh * 64 + r) * 1024 + tb * 64 + c8;
        *(bf16x8*)&buf[4][r][c8] = *(const bf16x8*)&kcth[ti];
        *(bf16x8*)&buf[5][r][c8] = *(const bf16x8*)&kctl[ti];
    }
    __syncthreads();
    #pragma unroll
    for (int kc = 0; kc < 2; ++kc) {
        int ar = 16 * w + (l & 15), ac = kc * 32 + (l >> 4) * 8;
        bf16x8 ah = *(const bf16x8*)&buf[2][ar][ac];
        bf16x8 al = *(const bf16x8*)&buf[3][ar][ac];
        #pragma unroll
        for (int cf = 0; cf < 4; ++cf) {
            int br = cf * 16 + (l & 15);
            bf16x8 bh_ = *(const bf16x8*)&buf[4][br][ac];
            bf16x8 bl_ = *(const bf16x8*)&buf[5][br][ac];
            o[cf] = MFMA16(ah, bh_, o[cf]);
            o[cf] = MFMA16(ah, bl_, o[cf]);
            o[cf] = MFMA16(al, bh_, o[cf]);
        }
    }
    // epilogue
    #pragma unroll
    for (int r = 0; r < 4; ++r) {
        int tl_ = 16 * w + 4 * (l >> 4) + r;
        float inv = 1.f / (cg_s[tl_] + EPS);
        float vv[4]; float sq = 0.f;
        #pragma unroll
        for (int cf = 0; cf < 4; ++cf) { vv[cf] = o[cf][r] * inv; sq += vv[cf] * vv[cf]; }
        #pragma unroll
        for (int off = 1; off < 16; off <<= 1) sq += __shfl_xor(sq, off);
        float scale = 1.f / fmaxf(sqrtf(sq), EPS);
        int tg = tb * 64 + tl_;
        #pragma unroll
        for (int cf = 0; cf < 4; ++cf) {
            int e = cf * 16 + (l & 15);
            size_t yi = ((size_t)b * 1024 + tg) * 512 + h * 64 + e;
            split2(vv[cf] * scale, &yh[yi], &yl[yi]);
        }
    }
}

// ---------------- output GEMM (split bf16): out = y @ WoT + bias (fp32) ----------------
__global__ void out_gemm(const u16* __restrict__ Ah, const u16* __restrict__ Al,
                         const u16* __restrict__ Bh, const u16* __restrict__ Bl,
                         const float* __restrict__ bias, float* __restrict__ out) {
    const int K = 512, N = 512;
    __shared__ __align__(16) u16 Ash[64][72], Asl[64][72], Bsh[64][72], Bsl[64][72];
    int tid = threadIdx.x, w = tid >> 6, l = tid & 63;
    int m0 = blockIdx.x * 64, n0 = blockIdx.y * 64;
    f32x4 acc[4] = {};
    for (int k0 = 0; k0 < K; k0 += 64) {
        #pragma unroll
        for (int p = 0; p < 2; ++p) {
            int i = tid + 256 * p; int r = i >> 3, c8 = (i & 7) * 8;
            *(bf16x8*)&Ash[r][c8] = *(const bf16x8*)&Ah[(size_t)(m0 + r) * K + k0 + c8];
            *(bf16x8*)&Asl[r][c8] = *(const bf16x8*)&Al[(size_t)(m0 + r) * K + k0 + c8];
            *(bf16x8*)&Bsh[r][c8] = *(const bf16x8*)&Bh[(size_t)(n0 + r) * K + k0 + c8];
            *(bf16x8*)&Bsl[r][c8] = *(const bf16x8*)&Bl[(size_t)(n0 + r) * K + k0 + c8];
        }
        __syncthreads();
        #pragma unroll
        for (int kc = 0; kc < 2; ++kc) {
            int ar = 16 * w + (l & 15), ac = kc * 32 + (l >> 4) * 8;
            bf16x8 ah = *(const bf16x8*)&Ash[ar][ac];
            bf16x8 al = *(const bf16x8*)&Asl[ar][ac];
            #pragma unroll
            for (int cf = 0; cf < 4; ++cf) {
                int br = cf * 16 + (l & 15);
                bf16x8 bh_ = *(const bf16x8*)&Bsh[br][ac];
                bf16x8 bl_ = *(const bf16x8*)&Bsl[br][ac];
                acc[cf] = MFMA16(ah, bh_, acc[cf]);
                acc[cf] = MFMA16(ah, bl_, acc[cf]);
                acc[cf] = MFMA16(al, bh_, acc[cf]);
            }
        }
        __syncthreads();
    }
    #pragma unroll
    for (int cf = 0; cf < 4; ++cf) {
        #pragma unroll
        for (int r = 0; r < 4; ++r) {
            int m = m0 + 16 * w + 4 * (l >> 4) + r;
            int n = n0 + 16 * cf + (l & 15);
            out[(size_t)m * N + n] = acc[cf][r] + bias[n];
        }
    }
}

extern "C" void kernel_launch(void* const* d_in, const int* in_sizes, int n_in,
                              void* d_out, int out_size, void* d_ws, size_t ws_size,
                              hipStream_t stream) {
    const float* x    = (const float*)d_in[0];
    const float* sbas = (const float*)d_in[1];
    const float* wq_w = (const float*)d_in[2];
    const float* wq_b = (const float*)d_in[3];
    const float* wk_w = (const float*)d_in[4];
    const float* wk_b = (const float*)d_in[5];
    const float* wv_w = (const float*)d_in[6];
    const float* wv_b = (const float*)d_in[7];
    const float* wo_w = (const float*)d_in[8];
    const float* wo_b = (const float*)d_in[9];
    const float* gw   = (const float*)d_in[10];
    const float* gb   = (const float*)d_in[11];
    float* out = (float*)d_out;

    char* p = (char*)d_ws;
    auto carve = [&](size_t bytes) { char* r = p; p += (bytes + 255) & ~(size_t)255; return r; };
    const size_t T2 = (size_t)2048 * 512 * 2;          // 2 MB (u16 plane)
    u16* xh = (u16*)carve(T2);      u16* xl = (u16*)carve(T2);
    u16* wqkvh = (u16*)carve((size_t)1536 * 512 * 2);
    u16* wqkvl = (u16*)carve((size_t)1536 * 512 * 2);
    u16* woh = (u16*)carve((size_t)512 * 512 * 2);
    u16* wol = (u16*)carve((size_t)512 * 512 * 2);
    u16* qh_ = (u16*)carve(T2);     u16* ql_ = (u16*)carve(T2);
    u16* kth_ = (u16*)carve(T2);    u16* ktl_ = (u16*)carve(T2);
    u16* vth_ = (u16*)carve(T2);    u16* vtl_ = (u16*)carve(T2);
    u16* kcrh_ = (u16*)carve(T2);   u16* kcrl_ = (u16*)carve(T2);
    u16* kcth_ = (u16*)carve(T2);   u16* kctl_ = (u16*)carve(T2);
    u16* vcrh_ = (u16*)carve(T2);   u16* vcrl_ = (u16*)carve(T2);
    u16* vcth_ = (u16*)carve(T2);   u16* vctl_ = (u16*)carve(T2);
    float* gbuf = (float*)carve((size_t)16 * 1024 * 4);
    float* cumg = (float*)carve((size_t)16 * 1024 * 4);
    float* Mst  = (float*)carve((size_t)16 * 16 * 4096 * 4);
    u16* pexh_ = (u16*)carve(T2);   u16* pexl_ = (u16*)carve(T2);
    u16* yh_ = (u16*)carve(T2);     u16* yl_ = (u16*)carve(T2);

    xconv_k<<<1024, 256, 0, stream>>>(x, xh, xl);
    wconv_k<<<dim3(8, 8, 4), 256, 0, stream>>>(wq_w, wk_w, wv_w, wo_w, wqkvh, wqkvl, woh, wol);
    qkv_gemm<<<dim3(32, 24), 256, 0, stream>>>(xh, xl, wqkvh, wqkvl, wq_b, wk_b, wv_b,
                                               qh_, ql_, kth_, ktl_, vth_, vtl_);
    conv_mfma<<<dim3(16, 16), 256, 0, stream>>>(kth_, ktl_, vth_, vtl_, sbas,
                                                kcrh_, kcrl_, kcth_, kctl_,
                                                vcrh_, vcrl_, vcth_, vctl_);
    gates_k<<<dim3(16, 16), 256, 0, stream>>>(kcrh_, kcrl_, vcrh_, vcrl_, gw, gb, gbuf);
    scan_k<<<16, 256, 0, stream>>>(gbuf, cumg);
    states_mfma<<<dim3(16, 16), 256, 0, stream>>>(kcth_, kctl_, vcth_, vctl_, gbuf, Mst);
    state_prefix<<<16, 256, 0, stream>>>(Mst, pexh_, pexl_);
    attn_mfma<<<dim3(16, 16), 256, 0, stream>>>(qh_, ql_, pexh_, pexl_, vcrh_, vcrl_,
                                                kcth_, kctl_, gbuf, cumg, yh_, yl_);
    out_gemm<<<dim3(32, 8), 256, 0, stream>>>(yh_, yl_, woh, wol, wo_b, out);
}

// Round 4
// 213.142 us; speedup vs baseline: 4.8733x; 1.0876x over previous
//
#include <hip/hip_runtime.h>
#include <math.h>

#define B 2
#define S 1024
#define DIM 512
#define H 8
#define HD 64
#define EPS 1e-5f

typedef __attribute__((ext_vector_type(8))) short bf16x8;
typedef __attribute__((ext_vector_type(4))) float f32x4;
typedef unsigned short u16;

__device__ inline u16 f2bf(float f) {
    unsigned int u = __float_as_uint(f);
    return (u16)((u + 0x7FFF + ((u >> 16) & 1)) >> 16);
}
__device__ inline float bf2f(u16 v) {
    return __uint_as_float(((unsigned int)v) << 16);
}
__device__ inline void split2(float x, u16* hi, u16* lo) {
    u16 h = f2bf(x);
    *hi = h;
    *lo = f2bf(x - bf2f(h));
}
#define MFMA16(a, b, c) __builtin_amdgcn_mfma_f32_16x16x32_bf16((a), (b), (c), 0, 0, 0)

// ---------------- x fp32 -> hi/lo bf16 planes ----------------
__global__ void xconv_k(const float* __restrict__ x, u16* __restrict__ xh, u16* __restrict__ xl) {
    int i = blockIdx.x * 256 + threadIdx.x;
    float4 v = ((const float4*)x)[i];
    ushort4 h, l;
    split2(v.x, &h.x, &l.x); split2(v.y, &h.y, &l.y);
    split2(v.z, &h.z, &l.z); split2(v.w, &h.w, &l.w);
    ((ushort4*)xh)[i] = h; ((ushort4*)xl)[i] = l;
}

// ---------------- weights: [K][N] f32 -> [N][K] hi/lo bf16 ----------------
__global__ void wconv_k(const float* __restrict__ wq, const float* __restrict__ wk,
                        const float* __restrict__ wv, const float* __restrict__ wo,
                        u16* __restrict__ wqkvh, u16* __restrict__ wqkvl,
                        u16* __restrict__ woh, u16* __restrict__ wol) {
    int z = blockIdx.z;
    const float* src = (z == 0) ? wq : (z == 1) ? wk : (z == 2) ? wv : wo;
    u16* dh = (z < 3) ? (wqkvh + (size_t)z * 512 * 512) : woh;
    u16* dl = (z < 3) ? (wqkvl + (size_t)z * 512 * 512) : wol;
    int k0 = blockIdx.x * 64, n0 = blockIdx.y * 64;
    int tid = threadIdx.x;
    __shared__ float T[64][65];
    #pragma unroll
    for (int p = 0; p < 16; ++p) {
        int i = tid + 256 * p; int r = i >> 6, c = i & 63;
        T[r][c] = src[(k0 + r) * 512 + n0 + c];
    }
    __syncthreads();
    #pragma unroll
    for (int p = 0; p < 16; ++p) {
        int i = tid + 256 * p; int r = i >> 6, c = i & 63;
        size_t di = (size_t)(n0 + r) * 512 + k0 + c;
        split2(T[c][r], &dh[di], &dl[di]);
    }
}

// ---------------- build Toeplitz filter tiles T[h][delta][t][s] ----------------
__global__ void toep_build(const float* __restrict__ filt,
                           u16* __restrict__ Th, u16* __restrict__ Tl) {
    int h = blockIdx.x, delta = blockIdx.y;
    int tid = threadIdx.x;
    size_t base = ((size_t)h * 16 + delta) << 12;
    #pragma unroll
    for (int p = 0; p < 16; ++p) {
        int i = tid + 256 * p;
        int t = i >> 6, s = i & 63;
        int idx = delta * 64 + t - s;
        float v = (idx >= 0 && idx < S) ? filt[idx * H + h] : 0.f;
        split2(v, &Th[base + i], &Tl[base + i]);
    }
}

// ---------------- zero fp32 accumulators ----------------
__global__ void zero_k(float* __restrict__ a) {
    int i = blockIdx.x * 256 + threadIdx.x;
    ((float4*)a)[i] = make_float4(0.f, 0.f, 0.f, 0.f);
}

// ---------------- QKV GEMM (split bf16): C = x @ Wt, scatter q/k/v ----------------
__global__ void qkv_gemm(const u16* __restrict__ Ah, const u16* __restrict__ Al,
                         const u16* __restrict__ Bh, const u16* __restrict__ Bl,
                         const float* __restrict__ bq, const float* __restrict__ bk,
                         const float* __restrict__ bv,
                         u16* __restrict__ qh, u16* __restrict__ ql,
                         u16* __restrict__ kth, u16* __restrict__ ktl,
                         u16* __restrict__ vth, u16* __restrict__ vtl) {
    const int K = 512;
    __shared__ __align__(16) u16 Ash[64][72], Asl[64][72], Bsh[64][72], Bsl[64][72];
    int tid = threadIdx.x, w = tid >> 6, l = tid & 63;
    int m0 = blockIdx.x * 64, n0 = blockIdx.y * 64;
    f32x4 acc[4] = {};
    for (int k0 = 0; k0 < K; k0 += 64) {
        #pragma unroll
        for (int p = 0; p < 2; ++p) {
            int i = tid + 256 * p; int r = i >> 3, c8 = (i & 7) * 8;
            *(bf16x8*)&Ash[r][c8] = *(const bf16x8*)&Ah[(size_t)(m0 + r) * K + k0 + c8];
            *(bf16x8*)&Asl[r][c8] = *(const bf16x8*)&Al[(size_t)(m0 + r) * K + k0 + c8];
            *(bf16x8*)&Bsh[r][c8] = *(const bf16x8*)&Bh[(size_t)(n0 + r) * K + k0 + c8];
            *(bf16x8*)&Bsl[r][c8] = *(const bf16x8*)&Bl[(size_t)(n0 + r) * K + k0 + c8];
        }
        __syncthreads();
        #pragma unroll
        for (int kc = 0; kc < 2; ++kc) {
            int ar = 16 * w + (l & 15), ac = kc * 32 + (l >> 4) * 8;
            bf16x8 ah = *(const bf16x8*)&Ash[ar][ac];
            bf16x8 al = *(const bf16x8*)&Asl[ar][ac];
            #pragma unroll
            for (int cf = 0; cf < 4; ++cf) {
                int br = cf * 16 + (l & 15);
                bf16x8 bh_ = *(const bf16x8*)&Bsh[br][ac];
                bf16x8 bl_ = *(const bf16x8*)&Bsl[br][ac];
                acc[cf] = MFMA16(ah, bh_, acc[cf]);
                acc[cf] = MFMA16(ah, bl_, acc[cf]);
                acc[cf] = MFMA16(al, bh_, acc[cf]);
            }
        }
        __syncthreads();
    }
    #pragma unroll
    for (int cf = 0; cf < 4; ++cf) {
        #pragma unroll
        for (int r = 0; r < 4; ++r) {
            int m = m0 + 16 * w + 4 * (l >> 4) + r;
            int n = n0 + 16 * cf + (l & 15);
            int bb = m >> 10, s = m & 1023;
            int which = n >> 9, nn = n & 511;
            int hh = nn >> 6, d = nn & 63;
            int bh = bb * 8 + hh;
            float val = acc[cf][r];
            if (which == 0) {
                val += bq[nn];
                size_t di = ((size_t)bh * 1024 + s) * 64 + d;
                split2(val, &qh[di], &ql[di]);
            } else if (which == 1) {
                val = (val + bk[nn]) * 0.125f;
                size_t di = ((size_t)bh * 64 + d) * 1024 + s;
                split2(val, &kth[di], &ktl[di]);
            } else {
                val += bv[nn];
                size_t di = ((size_t)bh * 64 + d) * 1024 + s;
                split2(val, &vth[di], &vtl[di]);
            }
        }
    }
}

// ---------------- split-K causal conv: partial accumulate into fp32 ----------------
#define NCH 4
#define CHW 4
__global__ void conv_part(const u16* __restrict__ kth, const u16* __restrict__ ktl,
                          const u16* __restrict__ vth, const u16* __restrict__ vtl,
                          const u16* __restrict__ Th, const u16* __restrict__ Tl,
                          float* __restrict__ Kacc, float* __restrict__ Vacc) {
    int tb = blockIdx.x, bh = blockIdx.y, ch = blockIdx.z;
    int h = bh & 7;
    int sb0 = ch * CHW;
    if (sb0 > tb) return;
    int sb1 = min(sb0 + CHW, tb + 1);
    int tid = threadIdx.x, w = tid >> 6, l = tid & 63;
    __shared__ __align__(16) u16 Ash[64][72], Asl[64][72];
    __shared__ __align__(16) u16 Ksh[64][72], Ksl[64][72], Vsh[64][72], Vsl[64][72];
    f32x4 aK[4] = {}, aV[4] = {};
    const size_t base = (size_t)bh * 64 * 1024;
    for (int sb = sb0; sb < sb1; ++sb) {
        size_t tbase = ((size_t)h * 16 + (tb - sb)) << 12;
        #pragma unroll
        for (int p = 0; p < 2; ++p) {
            int i = tid + 256 * p; int r = i >> 3, c8 = (i & 7) * 8;
            *(bf16x8*)&Ash[r][c8] = *(const bf16x8*)&Th[tbase + r * 64 + c8];
            *(bf16x8*)&Asl[r][c8] = *(const bf16x8*)&Tl[tbase + r * 64 + c8];
            *(bf16x8*)&Ksh[r][c8] = *(const bf16x8*)&kth[base + r * 1024 + sb * 64 + c8];
            *(bf16x8*)&Ksl[r][c8] = *(const bf16x8*)&ktl[base + r * 1024 + sb * 64 + c8];
            *(bf16x8*)&Vsh[r][c8] = *(const bf16x8*)&vth[base + r * 1024 + sb * 64 + c8];
            *(bf16x8*)&Vsl[r][c8] = *(const bf16x8*)&vtl[base + r * 1024 + sb * 64 + c8];
        }
        __syncthreads();
        #pragma unroll
        for (int kc = 0; kc < 2; ++kc) {
            int ar = 16 * w + (l & 15), ac = kc * 32 + (l >> 4) * 8;
            bf16x8 ah = *(const bf16x8*)&Ash[ar][ac];
            bf16x8 al = *(const bf16x8*)&Asl[ar][ac];
            #pragma unroll
            for (int cf = 0; cf < 4; ++cf) {
                int br = cf * 16 + (l & 15);
                bf16x8 kh8 = *(const bf16x8*)&Ksh[br][ac];
                bf16x8 kl8 = *(const bf16x8*)&Ksl[br][ac];
                bf16x8 vh8 = *(const bf16x8*)&Vsh[br][ac];
                bf16x8 vl8 = *(const bf16x8*)&Vsl[br][ac];
                aK[cf] = MFMA16(ah, kh8, aK[cf]);
                aK[cf] = MFMA16(ah, kl8, aK[cf]);
                aK[cf] = MFMA16(al, kh8, aK[cf]);
                aV[cf] = MFMA16(ah, vh8, aV[cf]);
                aV[cf] = MFMA16(ah, vl8, aV[cf]);
                aV[cf] = MFMA16(al, vh8, aV[cf]);
            }
        }
        __syncthreads();
    }
    #pragma unroll
    for (int cf = 0; cf < 4; ++cf) {
        #pragma unroll
        for (int r = 0; r < 4; ++r) {
            int tl_ = 16 * w + 4 * (l >> 4) + r;
            int d = cf * 16 + (l & 15);
            size_t oi = ((size_t)bh * 1024 + tb * 64 + tl_) * 64 + d;
            atomicAdd(&Kacc[oi], aK[cf][r]);
            atomicAdd(&Vacc[oi], aV[cf][r]);
        }
    }
}

// ---------------- finalize conv: split planes + gates (fused) ----------------
__global__ void conv_fin(const float* __restrict__ Kacc, const float* __restrict__ Vacc,
                         const float* __restrict__ gw, const float* __restrict__ gb,
                         u16* __restrict__ kcth, u16* __restrict__ kctl,
                         u16* __restrict__ vcrh, u16* __restrict__ vcrl,
                         u16* __restrict__ vcth, u16* __restrict__ vctl,
                         float* __restrict__ g) {
    int sc = blockIdx.x, bh = blockIdx.y;
    int tid = threadIdx.x, tx = tid & 63, ty = tid >> 6;
    __shared__ float Kt[64][65], Vt[64][65], G[64][65];
    for (int i = tid; i < 4096; i += 256) {
        int r = i >> 6, c = i & 63;
        G[r][c] = gw[i];
        Kt[r][c] = Kacc[(((size_t)bh * 1024) + sc * 64 + r) * 64 + c];
        Vt[r][c] = Vacc[(((size_t)bh * 1024) + sc * 64 + r) * 64 + c];
    }
    __syncthreads();
    float gbias = gb[0];
    // gates: one row per ty-group iteration
    #pragma unroll
    for (int it = 0; it < 16; ++it) {
        int sl = it * 4 + ty;
        float t = 0.f;
        #pragma unroll
        for (int e = 0; e < 64; ++e) t += G[tx][e] * Kt[sl][e];
        float p = Vt[sl][tx] * t;
        #pragma unroll
        for (int off = 32; off >= 1; off >>= 1) p += __shfl_xor(p, off);
        if (tx == 0) { float gg = fmaxf(p + gbias, 0.f); g[(size_t)bh * 1024 + sc * 64 + sl] = gg * gg + EPS; }
    }
    // row-major V planes (coalesced)
    #pragma unroll
    for (int it = 0; it < 16; ++it) {
        int r = it * 4 + ty;
        size_t ri = ((size_t)bh * 1024 + sc * 64 + r) * 64 + tx;
        split2(Vt[r][tx], &vcrh[ri], &vcrl[ri]);
    }
    // transposed planes (coalesced along t)
    #pragma unroll
    for (int it = 0; it < 16; ++it) {
        int d = it * 4 + ty;
        size_t ti = ((size_t)bh * 64 + d) * 1024 + sc * 64 + tx;
        split2(Kt[tx][d], &kcth[ti], &kctl[ti]);
        split2(Vt[tx][d], &vcth[ti], &vctl[ti]);
    }
}

// ---------------- inclusive scan of g -> cumg per bh ----------------
__global__ void scan_k(const float* __restrict__ g, float* __restrict__ cumg) {
    int bh = blockIdx.x; int tid = threadIdx.x;
    __shared__ float a0[1024], a1[1024];
    for (int i = tid; i < 1024; i += 256) a0[i] = g[(size_t)bh * 1024 + i];
    float *sp = a0, *dp = a1;
    for (int off = 1; off < 1024; off <<= 1) {
        __syncthreads();
        for (int i = tid; i < 1024; i += 256) dp[i] = sp[i] + (i >= off ? sp[i - off] : 0.f);
        float* tmp = sp; sp = dp; dp = tmp;
    }
    __syncthreads();
    for (int i = tid; i < 1024; i += 256) cumg[(size_t)bh * 1024 + i] = sp[i];
}

// ---------------- per-block states M[e][d] = sum_s g_s khat[s][e] vhat[s][d] ----------------
__global__ void states_mfma(const u16* __restrict__ kcth, const u16* __restrict__ kctl,
                            const u16* __restrict__ vcth, const u16* __restrict__ vctl,
                            const float* __restrict__ g, float* __restrict__ Mst) {
    int j = blockIdx.x, bh = blockIdx.y;
    int tid = threadIdx.x, w = tid >> 6, l = tid & 63;
    __shared__ __align__(16) u16 Ash[64][72], Asl[64][72], Bsh[64][72], Bsl[64][72];
    __shared__ float gs[64];
    if (tid < 64) gs[tid] = g[(size_t)bh * 1024 + j * 64 + tid];
    __syncthreads();
    #pragma unroll
    for (int p = 0; p < 2; ++p) {
        int i = tid + 256 * p; int r = i >> 3, c8 = (i & 7) * 8;
        bf16x8 kh8 = *(const bf16x8*)&kcth[((size_t)bh * 64 + r) * 1024 + j * 64 + c8];
        bf16x8 kl8 = *(const bf16x8*)&kctl[((size_t)bh * 64 + r) * 1024 + j * 64 + c8];
        #pragma unroll
        for (int q = 0; q < 8; ++q) {
            float f = (bf2f((u16)kh8[q]) + bf2f((u16)kl8[q])) * gs[c8 + q];
            split2(f, &Ash[r][c8 + q], &Asl[r][c8 + q]);
        }
        *(bf16x8*)&Bsh[r][c8] = *(const bf16x8*)&vcth[((size_t)bh * 64 + r) * 1024 + j * 64 + c8];
        *(bf16x8*)&Bsl[r][c8] = *(const bf16x8*)&vctl[((size_t)bh * 64 + r) * 1024 + j * 64 + c8];
    }
    __syncthreads();
    f32x4 acc[4] = {};
    #pragma unroll
    for (int kc = 0; kc < 2; ++kc) {
        int ar = 16 * w + (l & 15), ac = kc * 32 + (l >> 4) * 8;
        bf16x8 ah = *(const bf16x8*)&Ash[ar][ac];
        bf16x8 al = *(const bf16x8*)&Asl[ar][ac];
        #pragma unroll
        for (int cf = 0; cf < 4; ++cf) {
            int br = cf * 16 + (l & 15);
            bf16x8 bh_ = *(const bf16x8*)&Bsh[br][ac];
            bf16x8 bl_ = *(const bf16x8*)&Bsl[br][ac];
            acc[cf] = MFMA16(ah, bh_, acc[cf]);
            acc[cf] = MFMA16(ah, bl_, acc[cf]);
            acc[cf] = MFMA16(al, bh_, acc[cf]);
        }
    }
    #pragma unroll
    for (int cf = 0; cf < 4; ++cf) {
        #pragma unroll
        for (int r = 0; r < 4; ++r) {
            int e = 16 * w + 4 * (l >> 4) + r;
            int d = cf * 16 + (l & 15);
            Mst[(((size_t)bh * 16 + j) * 64 + e) * 64 + d] = acc[cf][r];
        }
    }
}

// ---------------- exclusive prefix over j -> hi/lo bf16 ----------------
__global__ void state_prefix(const float* __restrict__ Mst,
                             u16* __restrict__ ph, u16* __restrict__ pl) {
    int bh = blockIdx.x;
    int pos = blockIdx.y * 256 + threadIdx.x;
    float run = 0.f;
    #pragma unroll
    for (int j = 0; j < 16; ++j) {
        size_t idx = ((size_t)bh * 16 + j) * 4096 + pos;
        split2(run, &ph[idx], &pl[idx]);
        run += Mst[idx];
    }
}

// ---------------- attention: out = Q@Pex + intra, /(cumg+eps), unit-norm ----------------
__global__ void attn_mfma(const u16* __restrict__ qh, const u16* __restrict__ ql,
                          const u16* __restrict__ pexh, const u16* __restrict__ pexl,
                          const u16* __restrict__ vcrh, const u16* __restrict__ vcrl,
                          const u16* __restrict__ kcth, const u16* __restrict__ kctl,
                          const float* __restrict__ g, const float* __restrict__ cumg,
                          u16* __restrict__ yh, u16* __restrict__ yl) {
    int tb = blockIdx.x, bh = blockIdx.y;
    int b = bh >> 3, h = bh & 7;
    int tid = threadIdx.x, w = tid >> 6, l = tid & 63;
    __shared__ __align__(16) u16 buf[6][64][72];
    __shared__ float gl_s[64], cg_s[64];
    #pragma unroll
    for (int p = 0; p < 2; ++p) {
        int i = tid + 256 * p; int r = i >> 3, c8 = (i & 7) * 8;
        size_t rowi = ((size_t)bh * 1024 + tb * 64 + r) * 64 + c8;
        size_t pexi = (((size_t)bh * 16 + tb) * 64 + r) * 64 + c8;
        *(bf16x8*)&buf[0][r][c8] = *(const bf16x8*)&qh[rowi];
        *(bf16x8*)&buf[1][r][c8] = *(const bf16x8*)&ql[rowi];
        *(bf16x8*)&buf[2][r][c8] = *(const bf16x8*)&pexh[pexi];
        *(bf16x8*)&buf[3][r][c8] = *(const bf16x8*)&pexl[pexi];
        *(bf16x8*)&buf[4][r][c8] = *(const bf16x8*)&vcrh[rowi];
        *(bf16x8*)&buf[5][r][c8] = *(const bf16x8*)&vcrl[rowi];
    }
    if (tid < 64) {
        gl_s[tid] = g[(size_t)bh * 1024 + tb * 64 + tid];
        cg_s[tid] = cumg[(size_t)bh * 1024 + tb * 64 + tid];
    }
    __syncthreads();
    f32x4 o[4] = {}, sc[4] = {};
    #pragma unroll
    for (int kc = 0; kc < 2; ++kc) {
        int ar = 16 * w + (l & 15), ac = kc * 32 + (l >> 4) * 8;
        bf16x8 ah = *(const bf16x8*)&buf[0][ar][ac];
        bf16x8 al = *(const bf16x8*)&buf[1][ar][ac];
        #pragma unroll
        for (int cf = 0; cf < 4; ++cf) {
            int br = cf * 16 + (l & 15);
            bf16x8 bph = *(const bf16x8*)&buf[2][br][ac];
            bf16x8 bpl = *(const bf16x8*)&buf[3][br][ac];
            bf16x8 bvh = *(const bf16x8*)&buf[4][br][ac];
            bf16x8 bvl = *(const bf16x8*)&buf[5][br][ac];
            o[cf] = MFMA16(ah, bph, o[cf]);
            o[cf] = MFMA16(ah, bpl, o[cf]);
            o[cf] = MFMA16(al, bph, o[cf]);
            sc[cf] = MFMA16(ah, bvh, sc[cf]);
            sc[cf] = MFMA16(ah, bvl, sc[cf]);
            sc[cf] = MFMA16(al, bvh, sc[cf]);
        }
    }
    __syncthreads();
    #pragma unroll
    for (int cf = 0; cf < 4; ++cf) {
        int s = cf * 16 + (l & 15);
        float gsv = gl_s[s];
        #pragma unroll
        for (int r = 0; r < 4; ++r) {
            int t = 16 * w + 4 * (l >> 4) + r;
            float v = (s <= t) ? sc[cf][r] * gsv : 0.f;
            split2(v, &buf[2][t][s], &buf[3][t][s]);
        }
    }
    #pragma unroll
    for (int p = 0; p < 2; ++p) {
        int i = tid + 256 * p; int r = i >> 3, c8 = (i & 7) * 8;
        size_t ti = ((size_t)bh * 64 + r) * 1024 + tb * 64 + c8;
        *(bf16x8*)&buf[4][r][c8] = *(const bf16x8*)&kcth[ti];
        *(bf16x8*)&buf[5][r][c8] = *(const bf16x8*)&kctl[ti];
    }
    __syncthreads();
    #pragma unroll
    for (int kc = 0; kc < 2; ++kc) {
        int ar = 16 * w + (l & 15), ac = kc * 32 + (l >> 4) * 8;
        bf16x8 ah = *(const bf16x8*)&buf[2][ar][ac];
        bf16x8 al = *(const bf16x8*)&buf[3][ar][ac];
        #pragma unroll
        for (int cf = 0; cf < 4; ++cf) {
            int br = cf * 16 + (l & 15);
            bf16x8 bh_ = *(const bf16x8*)&buf[4][br][ac];
            bf16x8 bl_ = *(const bf16x8*)&buf[5][br][ac];
            o[cf] = MFMA16(ah, bh_, o[cf]);
            o[cf] = MFMA16(ah, bl_, o[cf]);
            o[cf] = MFMA16(al, bh_, o[cf]);
        }
    }
    #pragma unroll
    for (int r = 0; r < 4; ++r) {
        int tl_ = 16 * w + 4 * (l >> 4) + r;
        float inv = 1.f / (cg_s[tl_] + EPS);
        float vv[4]; float sq = 0.f;
        #pragma unroll
        for (int cf = 0; cf < 4; ++cf) { vv[cf] = o[cf][r] * inv; sq += vv[cf] * vv[cf]; }
        #pragma unroll
        for (int off = 1; off < 16; off <<= 1) sq += __shfl_xor(sq, off);
        float scale = 1.f / fmaxf(sqrtf(sq), EPS);
        int tg = tb * 64 + tl_;
        #pragma unroll
        for (int cf = 0; cf < 4; ++cf) {
            int e = cf * 16 + (l & 15);
            size_t yi = ((size_t)b * 1024 + tg) * 512 + h * 64 + e;
            split2(vv[cf] * scale, &yh[yi], &yl[yi]);
        }
    }
}

// ---------------- output GEMM (split bf16): out = y @ WoT + bias (fp32) ----------------
__global__ void out_gemm(const u16* __restrict__ Ah, const u16* __restrict__ Al,
                         const u16* __restrict__ Bh, const u16* __restrict__ Bl,
                         const float* __restrict__ bias, float* __restrict__ out) {
    const int K = 512, N = 512;
    __shared__ __align__(16) u16 Ash[64][72], Asl[64][72], Bsh[64][72], Bsl[64][72];
    int tid = threadIdx.x, w = tid >> 6, l = tid & 63;
    int m0 = blockIdx.x * 64, n0 = blockIdx.y * 64;
    f32x4 acc[4] = {};
    for (int k0 = 0; k0 < K; k0 += 64) {
        #pragma unroll
        for (int p = 0; p < 2; ++p) {
            int i = tid + 256 * p; int r = i >> 3, c8 = (i & 7) * 8;
            *(bf16x8*)&Ash[r][c8] = *(const bf16x8*)&Ah[(size_t)(m0 + r) * K + k0 + c8];
            *(bf16x8*)&Asl[r][c8] = *(const bf16x8*)&Al[(size_t)(m0 + r) * K + k0 + c8];
            *(bf16x8*)&Bsh[r][c8] = *(const bf16x8*)&Bh[(size_t)(n0 + r) * K + k0 + c8];
            *(bf16x8*)&Bsl[r][c8] = *(const bf16x8*)&Bl[(size_t)(n0 + r) * K + k0 + c8];
        }
        __syncthreads();
        #pragma unroll
        for (int kc = 0; kc < 2; ++kc) {
            int ar = 16 * w + (l & 15), ac = kc * 32 + (l >> 4) * 8;
            bf16x8 ah = *(const bf16x8*)&Ash[ar][ac];
            bf16x8 al = *(const bf16x8*)&Asl[ar][ac];
            #pragma unroll
            for (int cf = 0; cf < 4; ++cf) {
                int br = cf * 16 + (l & 15);
                bf16x8 bh_ = *(const bf16x8*)&Bsh[br][ac];
                bf16x8 bl_ = *(const bf16x8*)&Bsl[br][ac];
                acc[cf] = MFMA16(ah, bh_, acc[cf]);
                acc[cf] = MFMA16(ah, bl_, acc[cf]);
                acc[cf] = MFMA16(al, bh_, acc[cf]);
            }
        }
        __syncthreads();
    }
    #pragma unroll
    for (int cf = 0; cf < 4; ++cf) {
        #pragma unroll
        for (int r = 0; r < 4; ++r) {
            int m = m0 + 16 * w + 4 * (l >> 4) + r;
            int n = n0 + 16 * cf + (l & 15);
            out[(size_t)m * N + n] = acc[cf][r] + bias[n];
        }
    }
}

extern "C" void kernel_launch(void* const* d_in, const int* in_sizes, int n_in,
                              void* d_out, int out_size, void* d_ws, size_t ws_size,
                              hipStream_t stream) {
    const float* x    = (const float*)d_in[0];
    const float* sbas = (const float*)d_in[1];
    const float* wq_w = (const float*)d_in[2];
    const float* wq_b = (const float*)d_in[3];
    const float* wk_w = (const float*)d_in[4];
    const float* wk_b = (const float*)d_in[5];
    const float* wv_w = (const float*)d_in[6];
    const float* wv_b = (const float*)d_in[7];
    const float* wo_w = (const float*)d_in[8];
    const float* wo_b = (const float*)d_in[9];
    const float* gw   = (const float*)d_in[10];
    const float* gb   = (const float*)d_in[11];
    float* out = (float*)d_out;

    char* p = (char*)d_ws;
    auto carve = [&](size_t bytes) { char* r = p; p += (bytes + 255) & ~(size_t)255; return r; };
    const size_t T2 = (size_t)2048 * 512 * 2;          // 2 MB (u16 plane)
    u16* xh = (u16*)carve(T2);      u16* xl = (u16*)carve(T2);
    u16* wqkvh = (u16*)carve((size_t)1536 * 512 * 2);
    u16* wqkvl = (u16*)carve((size_t)1536 * 512 * 2);
    u16* woh = (u16*)carve((size_t)512 * 512 * 2);
    u16* wol = (u16*)carve((size_t)512 * 512 * 2);
    u16* qh_ = (u16*)carve(T2);     u16* ql_ = (u16*)carve(T2);
    u16* kth_ = (u16*)carve(T2);    u16* ktl_ = (u16*)carve(T2);
    u16* vth_ = (u16*)carve(T2);    u16* vtl_ = (u16*)carve(T2);
    u16* Tth = (u16*)carve((size_t)8 * 16 * 4096 * 2);
    u16* Ttl = (u16*)carve((size_t)8 * 16 * 4096 * 2);
    float* Kacc = (float*)carve((size_t)16 * 1024 * 64 * 4);
    float* Vacc = (float*)carve((size_t)16 * 1024 * 64 * 4);
    u16* kcth_ = (u16*)carve(T2);   u16* kctl_ = (u16*)carve(T2);
    u16* vcrh_ = (u16*)carve(T2);   u16* vcrl_ = (u16*)carve(T2);
    u16* vcth_ = (u16*)carve(T2);   u16* vctl_ = (u16*)carve(T2);
    float* gbuf = (float*)carve((size_t)16 * 1024 * 4);
    float* cumg = (float*)carve((size_t)16 * 1024 * 4);
    float* Mst  = (float*)carve((size_t)16 * 16 * 4096 * 4);
    u16* pexh_ = (u16*)carve(T2);   u16* pexl_ = (u16*)carve(T2);
    u16* yh_ = (u16*)carve(T2);     u16* yl_ = (u16*)carve(T2);

    xconv_k<<<1024, 256, 0, stream>>>(x, xh, xl);
    wconv_k<<<dim3(8, 8, 4), 256, 0, stream>>>(wq_w, wk_w, wv_w, wo_w, wqkvh, wqkvl, woh, wol);
    toep_build<<<dim3(8, 16), 256, 0, stream>>>(sbas, Tth, Ttl);
    zero_k<<<1024, 256, 0, stream>>>(Kacc);   // 4 MB
    zero_k<<<1024, 256, 0, stream>>>(Vacc);
    qkv_gemm<<<dim3(32, 24), 256, 0, stream>>>(xh, xl, wqkvh, wqkvl, wq_b, wk_b, wv_b,
                                               qh_, ql_, kth_, ktl_, vth_, vtl_);
    conv_part<<<dim3(16, 16, NCH), 256, 0, stream>>>(kth_, ktl_, vth_, vtl_, Tth, Ttl, Kacc, Vacc);
    conv_fin<<<dim3(16, 16), 256, 0, stream>>>(Kacc, Vacc, gw, gb,
                                               kcth_, kctl_, vcrh_, vcrl_, vcth_, vctl_, gbuf);
    scan_k<<<16, 256, 0, stream>>>(gbuf, cumg);
    states_mfma<<<dim3(16, 16), 256, 0, stream>>>(kcth_, kctl_, vcth_, vctl_, gbuf, Mst);
    state_prefix<<<dim3(16, 16), 256, 0, stream>>>(Mst, pexh_, pexl_);
    attn_mfma<<<dim3(16, 16), 256, 0, stream>>>(qh_, ql_, pexh_, pexl_, vcrh_, vcrl_,
                                                kcth_, kctl_, gbuf, cumg, yh_, yl_);
    out_gemm<<<dim3(32, 8), 256, 0, stream>>>(yh_, yl_, woh, wol, wo_b, out);
}